// Round 1
// baseline (265.921 us; speedup 1.0000x reference)
//
#include <hip/hip_runtime.h>
#include <hip/hip_bf16.h>

typedef __attribute__((ext_vector_type(8))) short short8;
typedef __attribute__((ext_vector_type(4))) float floatx4;
typedef __attribute__((ext_vector_type(4))) unsigned short ushort4v;

#define NQ 512
#define NH 100000
#define DM 256
#define BH 64

// LDS row strides in bf16 units; rows 16B-aligned, padded to break bank alignment
#define KSTR 264   // 256 + 8  -> 528 B rows
#define VSTR 72    // 64 + 8   -> 144 B rows
#define WSTR 72    // 64 + 8   -> 144 B rows

#define MFMA_BF16(a, b, c) __builtin_amdgcn_mfma_f32_16x16x32_bf16((a), (b), (c), 0, 0, 0)

__device__ __forceinline__ unsigned short f2bf(float f) {
    union { float f; unsigned u; } v; v.f = f;
    unsigned u = v.u + 0x7fffu + ((v.u >> 16) & 1u);   // round-to-nearest-even
    return (unsigned short)(u >> 16);
}

__global__ __launch_bounds__(512, 2)
void maskattn_phase1(const float* __restrict__ Qg,
                     const float* __restrict__ Kg,
                     const float* __restrict__ Vg,
                     const float* __restrict__ Mg,
                     float* __restrict__ numW,
                     float* __restrict__ denW,
                     int CH)
{
    __shared__ __attribute__((aligned(16))) unsigned short K_lds[64 * KSTR];
    __shared__ __attribute__((aligned(16))) unsigned short V_lds[256 * VSTR];  // transposed: [d][h]
    __shared__ __attribute__((aligned(16))) unsigned short w_lds[128 * WSTR];
    __shared__ float den_lds[2][128];

    const int tid  = threadIdx.x;
    const int lane = tid & 63;
    const int wid  = tid >> 6;     // 0..7
    const int wm   = wid >> 1;     // 0..3 : owns q rows 32*wm..+31 (block-local)
    const int wn   = wid & 1;      // 0..1 : S h-half / PV d-half
    const int g    = lane >> 4;    // 0..3
    const int l15  = lane & 15;

    const int qt    = blockIdx.x & 3;
    const int hc    = blockIdx.x >> 2;
    const int qbase = qt * 128;
    const long h0   = (long)hc * CH;
    const long hEnd = (h0 + CH < (long)NH) ? (h0 + CH) : (long)NH;

    // ---- Q fragments cached in registers: A[row=l15][k=8*g+i], d = 32*ks + 8*g + i ----
    short8 qa[2][8];
#pragma unroll
    for (int fq = 0; fq < 2; ++fq) {
        const float* qp = Qg + (size_t)(qbase + 32*wm + 16*fq + l15) * DM + 8*g;
#pragma unroll
        for (int ks = 0; ks < 8; ++ks) {
            floatx4 a = *(const floatx4*)(qp + 32*ks);
            floatx4 b = *(const floatx4*)(qp + 32*ks + 4);
            short8 fr;
            fr[0]=(short)f2bf(a[0]); fr[1]=(short)f2bf(a[1]);
            fr[2]=(short)f2bf(a[2]); fr[3]=(short)f2bf(a[3]);
            fr[4]=(short)f2bf(b[0]); fr[5]=(short)f2bf(b[1]);
            fr[6]=(short)f2bf(b[2]); fr[7]=(short)f2bf(b[3]);
            qa[fq][ks] = fr;
        }
    }

    floatx4 acc[2][8];
#pragma unroll
    for (int i = 0; i < 2; ++i)
#pragma unroll
        for (int j = 0; j < 8; ++j) {
            floatx4 z = {0.f, 0.f, 0.f, 0.f};
            acc[i][j] = z;
        }
    float dacc[8];
#pragma unroll
    for (int i = 0; i < 8; ++i) dacc[i] = 0.f;

    const int ntiles = (hEnd > h0) ? (int)((hEnd - h0 + BH - 1) / BH) : 0;

    for (int t = 0; t < ntiles; ++t) {
        const long hb = h0 + (long)t * BH;

        // ---- stage K tile: rows [hb..hb+63], f32 -> bf16, row-major ----
        {
            const int hr = tid >> 3;            // 0..63
            const int d0 = (tid & 7) * 4;       // lanes cover 128B contiguous per row chunk
            long krow = hb + hr; if (krow > (long)NH - 1) krow = (long)NH - 1;
            const float* kp = Kg + (size_t)krow * DM;
#pragma unroll
            for (int c = 0; c < 8; ++c) {
                const int d = d0 + 32*c;
                floatx4 v = *(const floatx4*)(kp + d);
                ushort4v p;
                p[0]=f2bf(v[0]); p[1]=f2bf(v[1]); p[2]=f2bf(v[2]); p[3]=f2bf(v[3]);
                *(ushort4v*)&K_lds[hr*KSTR + d] = p;
            }
        }
        // ---- stage V tile TRANSPOSED: V_lds[d][h] ----
        {
            const int dcol = tid & 63;
            const int hq0  = tid >> 6;          // 0..7
#pragma unroll
            for (int jh = 0; jh < 2; ++jh) {
                const int hq = hq0 + 8*jh;      // 0..15 -> h rows 4*hq..+3
#pragma unroll
                for (int jd = 0; jd < 4; ++jd) {
                    const int d = dcol + 64*jd;
                    ushort4v p;
#pragma unroll
                    for (int r = 0; r < 4; ++r) {
                        long hrow = hb + 4*hq + r; if (hrow > (long)NH - 1) hrow = (long)NH - 1;
                        p[r] = f2bf(Vg[(size_t)hrow * DM + d]);
                    }
                    *(ushort4v*)&V_lds[d*VSTR + 4*hq] = p;
                }
            }
        }
        __syncthreads();

        // ---- S = Q K^T (wave: 32q x 32h chunk at rows 32*wm, cols 32*wn) ----
        floatx4 sf[2][2];
        {
            floatx4 z = {0.f, 0.f, 0.f, 0.f};
            sf[0][0]=z; sf[0][1]=z; sf[1][0]=z; sf[1][1]=z;
        }
#pragma unroll
        for (int ks = 0; ks < 8; ++ks) {
            short8 kb0 = *(const short8*)&K_lds[(32*wn +      l15)*KSTR + 32*ks + 8*g];
            short8 kb1 = *(const short8*)&K_lds[(32*wn + 16 + l15)*KSTR + 32*ks + 8*g];
            sf[0][0] = MFMA_BF16(qa[0][ks], kb0, sf[0][0]);
            sf[0][1] = MFMA_BF16(qa[0][ks], kb1, sf[0][1]);
            sf[1][0] = MFMA_BF16(qa[1][ks], kb0, sf[1][0]);
            sf[1][1] = MFMA_BF16(qa[1][ks], kb1, sf[1][1]);
        }

        // ---- w = mask * exp(s/16); mask loaded straight from global in C-frag layout ----
#pragma unroll
        for (int fn = 0; fn < 2; ++fn) {
            const long h = hb + 32*wn + 16*fn + l15;
            const bool valid = (h < hEnd);
#pragma unroll
            for (int fq = 0; fq < 2; ++fq) {
#pragma unroll
                for (int j = 0; j < 4; ++j) {
                    const int rloc = 32*wm + 16*fq + 4*g + j;      // block-local q row
                    float m = valid ? Mg[(size_t)(qbase + rloc) * NH + h] : 0.f;
                    float s = sf[fq][fn][j] * 0.0625f;
                    s = (s > 60.f) ? 60.f : s;                     // inf guard for clamped tail rows
                    float w = m * __expf(s);
                    dacc[fq*4 + j] += w;
                    w_lds[rloc*WSTR + 32*wn + 16*fn + l15] = f2bf(w);
                }
            }
        }
        __syncthreads();

        // ---- PV: out(32q x 128d per wave) += w(.,64h) * V(64h, .) ----
#pragma unroll
        for (int ks = 0; ks < 2; ++ks) {
            short8 wa0 = *(const short8*)&w_lds[(32*wm +      l15)*WSTR + 32*ks + 8*g];
            short8 wa1 = *(const short8*)&w_lds[(32*wm + 16 + l15)*WSTR + 32*ks + 8*g];
#pragma unroll
            for (int fd = 0; fd < 8; ++fd) {
                short8 vb = *(const short8*)&V_lds[(128*wn + 16*fd + l15)*VSTR + 32*ks + 8*g];
                acc[0][fd] = MFMA_BF16(wa0, vb, acc[0][fd]);
                acc[1][fd] = MFMA_BF16(wa1, vb, acc[1][fd]);
            }
        }
        __syncthreads();
    }

    // ---- den: reduce across the 16 lanes sharing a row, combine wn halves via LDS ----
#pragma unroll
    for (int r = 0; r < 8; ++r) {
        float v = dacc[r];
        v += __shfl_xor(v, 1);
        v += __shfl_xor(v, 2);
        v += __shfl_xor(v, 4);
        v += __shfl_xor(v, 8);
        if (l15 == 0) {
            const int fq = r >> 2, j = r & 3;
            den_lds[wn][32*wm + 16*fq + 4*g + j] = v;
        }
    }
    __syncthreads();
    if (tid < 128) {
        denW[(size_t)hc * NQ + qbase + tid] = den_lds[0][tid] + den_lds[1][tid];
    }

    // ---- num partial write ----
#pragma unroll
    for (int fq = 0; fq < 2; ++fq)
#pragma unroll
        for (int fd = 0; fd < 8; ++fd)
#pragma unroll
            for (int j = 0; j < 4; ++j) {
                const int qrow = qbase + 32*wm + 16*fq + 4*g + j;
                const int d    = 128*wn + 16*fd + l15;
                numW[((size_t)hc * NQ + qrow) * DM + d] = acc[fq][fd][j];
            }
}

__global__ void maskattn_reduce(const float* __restrict__ numW,
                                const float* __restrict__ denW,
                                float* __restrict__ out, int C)
{
    const int q = blockIdx.x;
    const int d = threadIdx.x;
    float sn = 0.f, sd = 0.f;
    for (int c = 0; c < C; ++c) {
        sn += numW[((size_t)c * NQ + q) * DM + d];
        sd += denW[(size_t)c * NQ + q];
    }
    out[(size_t)q * DM + d] = sn / sd;
}

extern "C" void kernel_launch(void* const* d_in, const int* in_sizes, int n_in,
                              void* d_out, int out_size, void* d_ws, size_t ws_size,
                              hipStream_t stream)
{
    const float* Qg = (const float*)d_in[0];
    const float* Kg = (const float*)d_in[1];
    const float* Vg = (const float*)d_in[2];
    const float* Mg = (const float*)d_in[3];
    float* out = (float*)d_out;

    const size_t per_chunk = (size_t)NQ * DM * sizeof(float) + (size_t)NQ * sizeof(float);
    int C = (int)(ws_size / per_chunk);
    if (C > 64) C = 64;
    float* numW;
    float* denW;
    if (C >= 1) {
        numW = (float*)d_ws;
        denW = numW + (size_t)C * NQ * DM;
    } else {
        // emergency fallback: single chunk, accumulate numerator straight into out
        C = 1;
        numW = out;
        denW = (float*)d_ws;
    }
    const int ch64 = (NH + 64*C - 1) / (64*C);
    const int CH = 64 * ch64;

    maskattn_phase1<<<dim3(4 * C), dim3(512), 0, stream>>>(Qg, Kg, Vg, Mg, numW, denW, CH);
    maskattn_reduce<<<dim3(NQ), dim3(DM), 0, stream>>>(numW, denW, out, C);
}